// Round 1
// 258.935 us; speedup vs baseline: 1.0100x; 1.0100x over previous
//
#include <hip/hip_runtime.h>

// SortPredictionByEta: B=64, V=16384, F=32, C=4
// out[b,v,j] = frac[b,v, perm[b,j]] where perm ranks f by weighted eta ascending.

typedef float f32x4 __attribute__((ext_vector_type(4)));

constexpr int B = 64;
constexpr int V = 16384;
constexpr int F = 32;
constexpr int NCHUNK = 16;          // V-chunks per batch for deterministic reduction
constexpr int CHUNK = V / NCHUNK;   // 1024 rows per block
constexpr int ROWS = 128;           // rows per permute tile

// ---------------- Kernel 1: partial reductions over V ----------------
// grid = (NCHUNK, B), block = 256. Unchanged summation structure/order vs the
// 261us version (bit-exact ranking). feat loads are nontemporal (read-once,
// don't evict frac from L3 -- frac must stay resident for k_permute's re-read).
__global__ __launch_bounds__(256) void k_reduce(
    const float* __restrict__ frac, const float* __restrict__ feat,
    float* __restrict__ p1, float* __restrict__ p2)
{
    const int b     = blockIdx.y;
    const int chunk = blockIdx.x;
    const int tid   = threadIdx.x;
    const int v0    = chunk * CHUNK;

    __shared__ float2 sfeat[CHUNK];                // 8 KiB: {e, e*eta} per row
    const f32x4* feat4 = reinterpret_cast<const f32x4*>(feat);
    #pragma unroll
    for (int i = 0; i < CHUNK / 256; ++i) {
        const int r = tid + i * 256;
        const f32x4 f = __builtin_nontemporal_load(&feat4[b * V + v0 + r]);
        sfeat[r] = make_float2(f[0], f[0] * f[1]);
    }
    __syncthreads();

    const int g = tid & 7;
    const int w = tid >> 3;
    f32x4 a1 = {0.f, 0.f, 0.f, 0.f};
    f32x4 a2 = {0.f, 0.f, 0.f, 0.f};
    const f32x4* frac4 = reinterpret_cast<const f32x4*>(frac);

    for (int r = w; r < CHUNK; r += 32) {
        const float2 ee = sfeat[r];                // broadcast across 8 g-lanes
        const f32x4 fr = frac4[(b * V + v0 + r) * 8 + g];   // normal load: allocate in L2/L3
        a1 += ee.x * fr;
        a2 += ee.y * fr;
    }

    __shared__ float red[2][32][33];               // +1 pad: conflict-free reads
    const int f0 = 4 * g;
    red[0][w][f0+0] = a1[0]; red[0][w][f0+1] = a1[1]; red[0][w][f0+2] = a1[2]; red[0][w][f0+3] = a1[3];
    red[1][w][f0+0] = a2[0]; red[1][w][f0+1] = a2[1]; red[1][w][f0+2] = a2[2]; red[1][w][f0+3] = a2[3];
    __syncthreads();

    if (tid < 64) {
        const int which = tid >> 5;
        const int f     = tid & 31;
        float s = 0.f;
        #pragma unroll
        for (int j = 0; j < 32; ++j) s += red[which][j][f];
        float* dst = which ? p2 : p1;
        dst[(b * NCHUNK + chunk) * F + f] = s;
    }
}

// ---------------- Kernel 2: finalize + rank (once per batch) ----------------
// grid = (B), block = 64. Replaces the per-block redundant rank compute that
// every one of 16384 permute blocks used to do. Same chunk-sum order, same
// tie-break (top_k stability) and NaN semantics as the passing version.
__global__ __launch_bounds__(64) void k_rank(
    const float* __restrict__ p1, const float* __restrict__ p2,
    int* __restrict__ pm_g)
{
    const int b   = blockIdx.x;
    const int tid = threadIdx.x;
    __shared__ float wv[32];

    if (tid < 32) {
        float s1 = 0.f, s2 = 0.f;
        #pragma unroll
        for (int c = 0; c < NCHUNK; ++c) {
            s1 += p1[(b * NCHUNK + c) * F + tid];
            s2 += p2[(b * NCHUNK + c) * F + tid];
        }
        float we = s2 / (s1 + 1e-7f);
        // jnp.where(|we|>0.1, we, 500); NaN compares false -> 500 (matches jnp)
        we = (fabsf(we) > 0.1f) ? we : 500.0f;
        wv[tid] = we;
    }
    __syncthreads();
    if (tid < 32) {
        const float my = wv[tid];
        int rank = 0;
        #pragma unroll
        for (int j = 0; j < 32; ++j) {
            const float vj = wv[j];
            // ascending; ties broken by lower index first (top_k stability)
            rank += (vj < my || (vj == my && j < tid)) ? 1 : 0;
        }
        pm_g[b * 32 + rank] = tid;
    }
}

// ---------------- Kernel 3: permute ----------------
// grid = (V/ROWS, B) = (128, 64), block = 256. 128-row tiles: LDS 18.6 KiB ->
// 8 blocks/CU = full 32-wave occupancy; per-block fixed cost amortized over
// 2x the traffic of the old 64-row version, and the rank prologue is gone.
// frac reads nontemporal (last consumer); out stores nontemporal (streaming,
// keeps frac L3-resident for the blocks still to come).
__global__ __launch_bounds__(256) void k_permute(
    const float* __restrict__ frac,
    const int* __restrict__ pm_g,
    float* __restrict__ out)
{
    const int b   = blockIdx.y;
    const int tid = threadIdx.x;

    __shared__ int   pm[32];
    __shared__ float tile[ROWS * 36];              // stride 36: 16B-aligned rows, spread banks

    if (tid < 32) pm[tid] = pm_g[b * 32 + tid];

    const int vbase = blockIdx.x * ROWS;
    const int q  = tid & 7;                        // loop-invariant f-quad
    const int r0 = tid >> 3;                       // starting row within tile
    const f32x4* frac4 = reinterpret_cast<const f32x4*>(frac);

    #pragma unroll
    for (int i = 0; i < ROWS / 32; ++i) {          // 4 coalesced 16B/lane loads
        const int r = r0 + i * 32;
        const f32x4 v = __builtin_nontemporal_load(&frac4[(b * V + vbase + r) * 8 + q]);
        *reinterpret_cast<f32x4*>(&tile[r * 36 + q * 4]) = v;
    }
    __syncthreads();                               // covers pm + tile

    const int j0 = pm[4*q+0], j1 = pm[4*q+1], j2 = pm[4*q+2], j3 = pm[4*q+3];
    f32x4* out4 = reinterpret_cast<f32x4*>(out);
    #pragma unroll
    for (int i = 0; i < ROWS / 32; ++i) {
        const int r = r0 + i * 32;
        f32x4 o;
        o[0] = tile[r * 36 + j0];
        o[1] = tile[r * 36 + j1];
        o[2] = tile[r * 36 + j2];
        o[3] = tile[r * 36 + j3];
        __builtin_nontemporal_store(o, &out4[(b * V + vbase + r) * 8 + q]);
    }
}

extern "C" void kernel_launch(void* const* d_in, const int* in_sizes, int n_in,
                              void* d_out, int out_size, void* d_ws, size_t ws_size,
                              hipStream_t stream)
{
    const float* frac = (const float*)d_in[0];   // (B,V,F) f32
    const float* feat = (const float*)d_in[1];   // (B,V,C) f32
    float* out = (float*)d_out;                  // (B,V,F) f32

    // workspace: p1[B][NCHUNK][F], p2[B][NCHUNK][F] (256 KiB) + pm[B][32] (8 KiB)
    float* p1 = (float*)d_ws;
    float* p2 = p1 + B * NCHUNK * F;
    int*   pm = (int*)(p2 + B * NCHUNK * F);

    k_reduce <<<dim3(NCHUNK, B), 256, 0, stream>>>(frac, feat, p1, p2);
    k_rank   <<<dim3(B),         64, 0, stream>>>(p1, p2, pm);
    k_permute<<<dim3(V / ROWS, B), 256, 0, stream>>>(frac, pm, out);
}